// Round 2
// baseline (35349.103 us; speedup 1.0000x reference)
//
#include <hip/hip_runtime.h>
#include <cstddef>

// Problem constants
#define TT 512
#define BB 64
#define EE 512
#define N3 1536   // 3*EE

// ---------------------------------------------------------------------------
// Embedding gather: xout[i][:] = emb[idx[i]][:], i = t*B+b
// ---------------------------------------------------------------------------
__global__ void embed_k(const int* __restrict__ idx, const float* __restrict__ emb,
                        float* __restrict__ xout) {
    const int i = blockIdx.x;                 // 0..T*B-1
    const int row = idx[i];
    const float4* s = (const float4*)(emb + (size_t)row * EE);
    float4* d = (float4*)(xout + (size_t)i * EE);
    d[threadIdx.x] = s[threadIdx.x];          // 128 threads * float4 = 512 floats
}

// ---------------------------------------------------------------------------
// x_proj GEMM: C[M][N] = A[M][K] * W[N][K]^T + bias[N]
// M=32768, N=1536, K=512. 128x128 tile, 8x8 per thread, fp32.
// ---------------------------------------------------------------------------
__global__ __launch_bounds__(256)
void gemm_xp(const float* __restrict__ A, const float* __restrict__ W,
             const float* __restrict__ bias, float* __restrict__ C) {
    constexpr int K = EE, N = N3;
    __shared__ float As[16][132];
    __shared__ float Bs[16][132];
    const int tid = threadIdx.x;
    const int tx = tid & 15, ty = tid >> 4;
    const int m0 = blockIdx.y * 128, n0 = blockIdx.x * 128;
    const int r = tid >> 1;            // 0..127
    const int kq = (tid & 1) * 8;      // 0 or 8
    const float* Ap = A + (size_t)(m0 + r) * K + kq;
    const float* Wp = W + (size_t)(n0 + r) * K + kq;

    float acc[8][8];
#pragma unroll
    for (int i = 0; i < 8; ++i)
#pragma unroll
        for (int j = 0; j < 8; ++j) acc[i][j] = 0.f;

    for (int k0 = 0; k0 < K; k0 += 16) {
        float4 a0 = *(const float4*)(Ap + k0);
        float4 a1 = *(const float4*)(Ap + k0 + 4);
        float4 b0 = *(const float4*)(Wp + k0);
        float4 b1 = *(const float4*)(Wp + k0 + 4);
        __syncthreads();
        As[kq+0][r] = a0.x; As[kq+1][r] = a0.y; As[kq+2][r] = a0.z; As[kq+3][r] = a0.w;
        As[kq+4][r] = a1.x; As[kq+5][r] = a1.y; As[kq+6][r] = a1.z; As[kq+7][r] = a1.w;
        Bs[kq+0][r] = b0.x; Bs[kq+1][r] = b0.y; Bs[kq+2][r] = b0.z; Bs[kq+3][r] = b0.w;
        Bs[kq+4][r] = b1.x; Bs[kq+5][r] = b1.y; Bs[kq+6][r] = b1.z; Bs[kq+7][r] = b1.w;
        __syncthreads();
#pragma unroll
        for (int kk = 0; kk < 16; ++kk) {
            float av[8], bv[8];
            *(float4*)&av[0] = *(const float4*)&As[kk][ty*8];
            *(float4*)&av[4] = *(const float4*)&As[kk][ty*8+4];
            *(float4*)&bv[0] = *(const float4*)&Bs[kk][tx*8];
            *(float4*)&bv[4] = *(const float4*)&Bs[kk][tx*8+4];
#pragma unroll
            for (int i = 0; i < 8; ++i)
#pragma unroll
                for (int j = 0; j < 8; ++j)
                    acc[i][j] += av[i] * bv[j];
        }
    }
#pragma unroll
    for (int i = 0; i < 8; ++i) {
        float* Crow = C + (size_t)(m0 + ty*8 + i) * N + n0 + tx*8;
#pragma unroll
        for (int j = 0; j < 8; ++j)
            Crow[j] = acc[i][j] + bias[n0 + tx*8 + j];
    }
}

// ---------------------------------------------------------------------------
// GRU recurrence for one layer. 256 blocks x 256 threads, persistent, 1/CU.
// Block owns e-slice [2*blk, 2*blk+2) -> 6 Whh rows kept in VGPRs/AGPRs.
// Thread (bt = tid>>4, kc = tid&15): batches 4*bt..+3, k-chunk kc*32..+31.
//
// Cross-block h exchange: agent-scope RELAXED atomics (global_* sc1) that
// bypass the non-coherent per-XCD L2 and hit the Infinity Cache directly.
// NO __threadfence (no buffer_wbl2/buffer_inv) -> L2 stays warm for xp.
// Barrier: per-thread s_waitcnt(0) drain, then 16x16 two-level monotonic
// epoch counters with relaxed agent atomics.
// ---------------------------------------------------------------------------
__global__ __launch_bounds__(256, 1)
void gru_scan(const float* __restrict__ xp,   // [T][B][3E] (includes b_ih)
              const float* __restrict__ Whh,  // [3E][E] this layer
              const float* __restrict__ bhh,  // [3E]   this layer
              const int* __restrict__ lens,   // [B]
              float* __restrict__ y,          // [T][B][E]
              float* __restrict__ hA, float* __restrict__ hB,  // [B][E] each
              float* __restrict__ finals,     // [B][E]
              unsigned* __restrict__ ctrl, unsigned ebase)
{
    const int e0 = blockIdx.x * 2;
    const int tid = threadIdx.x;
    const int kc = tid & 15;
    const int bt = tid >> 4;
    const int kbase = kc * 32;

    // weights in registers: w[c][k], c = {r0,r1,z0,z1,n0,n1}
    float w[6][32];
#pragma unroll
    for (int c = 0; c < 6; ++c) {
        const int row = (c >> 1) * EE + e0 + (c & 1);
        const float4* wp = (const float4*)(Whh + (size_t)row * EE + kbase);
#pragma unroll
        for (int q = 0; q < 8; ++q) {
            float4 v = wp[q];
            w[c][q*4+0] = v.x; w[c][q*4+1] = v.y;
            w[c][q*4+2] = v.z; w[c][q*4+3] = v.w;
        }
    }
    float bh[6];
#pragma unroll
    for (int c = 0; c < 6; ++c) bh[c] = bhh[(c >> 1) * EE + e0 + (c & 1)];
    int mylen[4];
#pragma unroll
    for (int bi = 0; bi < 4; ++bi) mylen[bi] = lens[bt * 4 + bi];
    float hreg[4][2] = {{0.f, 0.f}, {0.f, 0.f}, {0.f, 0.f}, {0.f, 0.f}};

    unsigned* gcnt = ctrl + (blockIdx.x & 15u) * 32;   // 16 groups, 128B apart
    unsigned* gl   = ctrl + 512;

    for (int t = 0; t < TT; ++t) {
        float* hc = (t & 1) ? hB : hA;   // current h (read)
        float* hn = (t & 1) ? hA : hB;   // next h (write)

        // ---- xp prefetch for this step (independent of h; hides HBM lat) ----
        float xv[4][2][3];
        if (kc == 0) {
            const float* xpt = xp + (size_t)t * BB * N3;
#pragma unroll
            for (int bi = 0; bi < 4; ++bi) {
                const float* xpb = xpt + (size_t)(bt * 4 + bi) * N3;
#pragma unroll
                for (int ei = 0; ei < 2; ++ei) {
                    xv[bi][ei][0] = xpb[e0 + ei];
                    xv[bi][ei][1] = xpb[EE + e0 + ei];
                    xv[bi][ei][2] = xpb[2 * EE + e0 + ei];
                }
            }
        }

        // ---- h loads (IC-coherent atomics) + dot products ----
        float acc[6][4];
#pragma unroll
        for (int c = 0; c < 6; ++c)
#pragma unroll
            for (int bi = 0; bi < 4; ++bi) acc[c][bi] = 0.f;

#pragma unroll
        for (int bi = 0; bi < 4; ++bi) {
            unsigned long long* hp =
                (unsigned long long*)(hc + (size_t)(bt * 4 + bi) * EE + kbase);
            float2 hv[16];
#pragma unroll
            for (int q = 0; q < 16; ++q) {
                unsigned long long u = __hip_atomic_load(
                    hp + q, __ATOMIC_RELAXED, __HIP_MEMORY_SCOPE_AGENT);
                hv[q] = __builtin_bit_cast(float2, u);
            }
#pragma unroll
            for (int q = 0; q < 16; ++q) {
#pragma unroll
                for (int c = 0; c < 6; ++c) {
                    acc[c][bi] += w[c][q*2+0] * hv[q].x + w[c][q*2+1] * hv[q].y;
                }
            }
        }

        // reduce partial dots across the 16 kc lanes (lane bits 0..3)
#pragma unroll
        for (int m = 1; m < 16; m <<= 1) {
#pragma unroll
            for (int c = 0; c < 6; ++c)
#pragma unroll
                for (int bi = 0; bi < 4; ++bi)
                    acc[c][bi] += __shfl_xor(acc[c][bi], m, 64);
        }

        // ---- gates + h/y stores (kc==0 lanes) ----
        if (kc == 0) {
#pragma unroll
            for (int bi = 0; bi < 4; ++bi) {
                const int b = bt * 4 + bi;
                const bool msk = (t < mylen[bi]);
                float hout2[2];
#pragma unroll
                for (int ei = 0; ei < 2; ++ei) {
                    const float xr = xv[bi][ei][0], xz = xv[bi][ei][1],
                                xn = xv[bi][ei][2];
                    const float hr = acc[0+ei][bi] + bh[0+ei];
                    const float hz = acc[2+ei][bi] + bh[2+ei];
                    const float hv = acc[4+ei][bi] + bh[4+ei];
                    const float rg = 1.f / (1.f + __expf(-(xr + hr)));
                    const float zg = 1.f / (1.f + __expf(-(xz + hz)));
                    const float ng = tanhf(xn + rg * hv);
                    const float hold = hreg[bi][ei];
                    const float hnew = (1.f - zg) * ng + zg * hold;
                    const float hout = msk ? hnew : hold;
                    hreg[bi][ei] = hout;
                    hout2[ei] = hout;
                    y[((size_t)t * BB + b) * EE + e0 + ei] = msk ? hout : 0.f;
                    if (t == TT - 1) finals[(size_t)b * EE + e0 + ei] = hout;
                }
                // 8B write-through store of the h pair (e0 even -> aligned)
                float2 hp2; hp2.x = hout2[0]; hp2.y = hout2[1];
                __hip_atomic_store(
                    (unsigned long long*)(hn + (size_t)b * EE + e0),
                    __builtin_bit_cast(unsigned long long, hp2),
                    __ATOMIC_RELAXED, __HIP_MEMORY_SCOPE_AGENT);
            }
        }

        // ---- fence-free grid barrier, monotonic epoch ----
        const unsigned e = ebase + (unsigned)t + 1u;
        __builtin_amdgcn_s_waitcnt(0);   // drain h stores to coherence point
        __syncthreads();
        if (tid == 0) {
            unsigned a = __hip_atomic_fetch_add(gcnt, 1u, __ATOMIC_RELAXED,
                                                __HIP_MEMORY_SCOPE_AGENT);
            if (a == 16u * e - 1u)
                __hip_atomic_fetch_add(gl, 1u, __ATOMIC_RELAXED,
                                       __HIP_MEMORY_SCOPE_AGENT);
            while (__hip_atomic_load(gl, __ATOMIC_RELAXED,
                                     __HIP_MEMORY_SCOPE_AGENT) < 16u * e)
                __builtin_amdgcn_s_sleep(2);
        }
        __syncthreads();
    }
}

// ---------------------------------------------------------------------------
extern "C" void kernel_launch(void* const* d_in, const int* in_sizes, int n_in,
                              void* d_out, int out_size, void* d_ws, size_t ws_size,
                              hipStream_t stream) {
    const int* input_batch  = (const int*)d_in[0];
    const int* lens         = (const int*)d_in[1];
    const float* emb        = (const float*)d_in[2];
    const float* W_ih       = (const float*)d_in[3];
    const float* W_hh       = (const float*)d_in[4];
    const float* b_ih       = (const float*)d_in[5];
    const float* b_hh       = (const float*)d_in[6];
    float* out = (float*)d_out;
    float* ws  = (float*)d_ws;

    // workspace layout (float offsets)
    const size_t XPROJ = 0;                          // [T][B][3E] = 50331648
    const size_t XBUF  = (size_t)TT * BB * N3;       // x_emb, then ys0: 16777216
    const size_t H0    = XBUF + (size_t)TT * BB * EE;
    const size_t H1    = H0 + (size_t)BB * EE;
    const size_t CTRL  = H1 + (size_t)BB * EE;
    if (ws_size < (CTRL + 1024) * sizeof(float)) return;  // ~269 MB needed

    float* xproj = ws + XPROJ;
    float* xbuf  = ws + XBUF;
    float* h0    = ws + H0;
    float* h1    = ws + H1;
    unsigned* ctrl = (unsigned*)(ws + CTRL);

    const size_t OUT_YS = 0;                              // [T][B][E]
    const size_t OUT_FIN = (size_t)TT * BB * EE;          // [L][B][E]

    // zero h ping-pong buffers + barrier control (ws is poisoned 0xAA)
    hipMemsetAsync(h0, 0, (2 * (size_t)BB * EE + 1024) * sizeof(float), stream);

    // x = emb[input_batch]
    embed_k<<<dim3(TT * BB), dim3(128), 0, stream>>>(input_batch, emb, xbuf);

    // ---- layer 0 ----
    gemm_xp<<<dim3(N3 / 128, (TT * BB) / 128), dim3(256), 0, stream>>>(
        xbuf, W_ih, b_ih, xproj);
    gru_scan<<<dim3(256), dim3(256), 0, stream>>>(
        xproj, W_hh, b_hh, lens,
        xbuf /* ys0 (x_emb is dead now) */, h0, h1,
        out + OUT_FIN /* finals layer 0 */, ctrl, 0u);

    // ---- layer 1 ----
    gemm_xp<<<dim3(N3 / 128, (TT * BB) / 128), dim3(256), 0, stream>>>(
        xbuf, W_ih + (size_t)N3 * EE, b_ih + N3, xproj);
    hipMemsetAsync(h0, 0, 2 * (size_t)BB * EE * sizeof(float), stream);
    gru_scan<<<dim3(256), dim3(256), 0, stream>>>(
        xproj, W_hh + (size_t)N3 * EE, b_hh + N3, lens,
        out + OUT_YS /* ys1 = output x */, h0, h1,
        out + OUT_FIN + (size_t)BB * EE /* finals layer 1 */, ctrl, 512u);
}

// Round 4
// 12160.454 us; speedup vs baseline: 2.9069x; 2.9069x over previous
//
#include <hip/hip_runtime.h>
#include <cstddef>

// Problem constants
#define TT 512
#define BB 64
#define EE 512
#define N3 1536   // 3*EE

// GRU scan decomposition: 8 batch-groups x 8 batches; 32 blocks/group,
// each block owns 16 e-columns. 256 blocks total, 1 per CU.
#define GRP 8
#define BPG 32
#define BATG 8
#define EPB 16

// ---------------------------------------------------------------------------
// Coherent (cross-XCD, IC-level) access helpers: sc0 sc1 = bypass L1+L2,
// read/write at the device coherence point. Pipelined (no per-op waitcnt).
// ---------------------------------------------------------------------------
__device__ __forceinline__ float4 load_coh_x4(const float4* p) {
    float4 r;
    asm volatile("global_load_dwordx4 %0, %1, off sc0 sc1" : "=v"(r) : "v"(p));
    return r;
}
__device__ __forceinline__ void store_coh(float* p, float v) {
    asm volatile("global_store_dword %0, %1, off sc0 sc1" :: "v"(p), "v"(v) : "memory");
}
__device__ __forceinline__ void wait_vm0() {
    // Volatile asm with memory clobber: later memory ops (LDS stores) cannot
    // be hoisted above it; earlier volatile-asm loads cannot sink below it.
    asm volatile("s_waitcnt vmcnt(0)" ::: "memory");
}

// ---------------------------------------------------------------------------
// Embedding gather: xout[i][:] = emb[idx[i]][:], i = t*B+b
// ---------------------------------------------------------------------------
__global__ void embed_k(const int* __restrict__ idx, const float* __restrict__ emb,
                        float* __restrict__ xout) {
    const int i = blockIdx.x;                 // 0..T*B-1
    const int row = idx[i];
    const float4* s = (const float4*)(emb + (size_t)row * EE);
    float4* d = (float4*)(xout + (size_t)i * EE);
    d[threadIdx.x] = s[threadIdx.x];          // 128 threads * float4 = 512 floats
}

// ---------------------------------------------------------------------------
// x_proj GEMM: C[M][N] = A[M][K] * W[N][K]^T + bias[N]
// M=32768, N=1536, K=512. 128x128 tile, 8x8 per thread, fp32.
// ---------------------------------------------------------------------------
__global__ __launch_bounds__(256)
void gemm_xp(const float* __restrict__ A, const float* __restrict__ W,
             const float* __restrict__ bias, float* __restrict__ C) {
    constexpr int K = EE, N = N3;
    __shared__ float As[16][132];
    __shared__ float Bs[16][132];
    const int tid = threadIdx.x;
    const int tx = tid & 15, ty = tid >> 4;
    const int m0 = blockIdx.y * 128, n0 = blockIdx.x * 128;
    const int r = tid >> 1;            // 0..127
    const int kq = (tid & 1) * 8;      // 0 or 8
    const float* Ap = A + (size_t)(m0 + r) * K + kq;
    const float* Wp = W + (size_t)(n0 + r) * K + kq;

    float acc[8][8];
#pragma unroll
    for (int i = 0; i < 8; ++i)
#pragma unroll
        for (int j = 0; j < 8; ++j) acc[i][j] = 0.f;

    for (int k0 = 0; k0 < K; k0 += 16) {
        float4 a0 = *(const float4*)(Ap + k0);
        float4 a1 = *(const float4*)(Ap + k0 + 4);
        float4 b0 = *(const float4*)(Wp + k0);
        float4 b1 = *(const float4*)(Wp + k0 + 4);
        __syncthreads();
        As[kq+0][r] = a0.x; As[kq+1][r] = a0.y; As[kq+2][r] = a0.z; As[kq+3][r] = a0.w;
        As[kq+4][r] = a1.x; As[kq+5][r] = a1.y; As[kq+6][r] = a1.z; As[kq+7][r] = a1.w;
        Bs[kq+0][r] = b0.x; Bs[kq+1][r] = b0.y; Bs[kq+2][r] = b0.z; Bs[kq+3][r] = b0.w;
        Bs[kq+4][r] = b1.x; Bs[kq+5][r] = b1.y; Bs[kq+6][r] = b1.z; Bs[kq+7][r] = b1.w;
        __syncthreads();
#pragma unroll
        for (int kk = 0; kk < 16; ++kk) {
            float av[8], bv[8];
            *(float4*)&av[0] = *(const float4*)&As[kk][ty*8];
            *(float4*)&av[4] = *(const float4*)&As[kk][ty*8+4];
            *(float4*)&bv[0] = *(const float4*)&Bs[kk][tx*8];
            *(float4*)&bv[4] = *(const float4*)&Bs[kk][tx*8+4];
#pragma unroll
            for (int i = 0; i < 8; ++i)
#pragma unroll
                for (int j = 0; j < 8; ++j)
                    acc[i][j] += av[i] * bv[j];
        }
    }
#pragma unroll
    for (int i = 0; i < 8; ++i) {
        float* Crow = C + (size_t)(m0 + ty*8 + i) * N + n0 + tx*8;
#pragma unroll
        for (int j = 0; j < 8; ++j)
            Crow[j] = acc[i][j] + bias[n0 + tx*8 + j];
    }
}

// ---------------------------------------------------------------------------
// GRU recurrence, batch-grouped. Block = (group g = blockIdx&7, slice sl).
// Group g owns batches [8g, 8g+8); block owns e in [16*sl, 16*sl+16).
// Thread (kc = tid&15 -> k-chunk of 32, et = tid>>4 -> e = e0+et) holds
// Whh rows (r,z,n at its e) x 32 k = 96 weight floats in VGPRs.
// Per step: stage group h-slice (16KB) to LDS (coherent dwordx4 loads,
// XOR-swizzled units -> 2-way-max bank conflicts), dot products, shuffle
// k-reduction, gates on kc==0 lanes, coherent h stores, 32-wide group
// barrier on a monotonic epoch counter.
// ---------------------------------------------------------------------------
__global__ __launch_bounds__(256, 1)
void gru_scan(const float* __restrict__ xp,   // [T][B][3E] (includes b_ih)
              const float* __restrict__ Whh,  // [3E][E] this layer
              const float* __restrict__ bhh,  // [3E]   this layer
              const int* __restrict__ lens,   // [B]
              float* __restrict__ y,          // [T][B][E]
              float* __restrict__ hbuf,       // [GRP][2][BATG][EE]
              float* __restrict__ finals,     // [B][E]
              unsigned* __restrict__ ctrl, unsigned ebase)
{
    const int g  = blockIdx.x & 7;         // batch group
    const int sl = blockIdx.x >> 3;        // e-slice 0..31
    const int e0 = sl * EPB;
    const int tid = threadIdx.x;
    const int kc = tid & 15;               // k-chunk (32 floats)
    const int et = tid >> 4;               // e within block
    const int e  = e0 + et;
    const int b0 = g * BATG;

    // ---- weights: rows (r,z,n at e), k-chunk kc*32..+31 ----
    float w[3][32];
#pragma unroll
    for (int c = 0; c < 3; ++c) {
        const float* wr = Whh + (size_t)(c * EE + e) * EE + kc * 32;
#pragma unroll
        for (int q = 0; q < 8; ++q) {
            float4 v = ((const float4*)wr)[q];
            w[c][q*4+0] = v.x; w[c][q*4+1] = v.y;
            w[c][q*4+2] = v.z; w[c][q*4+3] = v.w;
        }
    }
    float bh[3];
#pragma unroll
    for (int c = 0; c < 3; ++c) bh[c] = bhh[c * EE + e];
    int mylen[BATG];
#pragma unroll
    for (int bi = 0; bi < BATG; ++bi) mylen[bi] = lens[b0 + bi];
    float hreg[BATG];
#pragma unroll
    for (int bi = 0; bi < BATG; ++bi) hreg[bi] = 0.f;

    float* hA = hbuf + (size_t)g * 2 * BATG * EE;
    float* hB = hA + BATG * EE;
    unsigned* gc = ctrl + g * 32;          // per-group counter, 128B apart

    // stager identity: thread stages 64B (4 units of 16B) of the 16KB slice
    const int sb  = tid >> 5;              // batch 0..7
    const int scu = (tid & 31) * 4;        // first 16B-unit within batch row
    const int sxr = ((tid & 31) >> 1) & 7; // XOR swizzle for those 4 units

    __shared__ float hs[BATG * EE];        // 16KB, unit-swizzled per row

    for (int t = 0; t < TT; ++t) {
        const float* hc = (t & 1) ? hB : hA;
        float* hn = (t & 1) ? hA : hB;

        // ---- xp prefetch (independent of h; hides HBM latency) ----
        float xv[BATG][3];
        if (kc == 0) {
            const float* xpt = xp + (size_t)t * BB * N3;
#pragma unroll
            for (int bi = 0; bi < BATG; ++bi) {
                const float* xpb = xpt + (size_t)(b0 + bi) * N3;
#pragma unroll
                for (int c = 0; c < 3; ++c) xv[bi][c] = xpb[c * EE + e];
            }
        }

        // ---- stage h slice to LDS: 4 coherent dwordx4 loads, pipelined ----
        const float4* gp = (const float4*)(hc + (size_t)sb * EE);
        float4 g0 = load_coh_x4(gp + scu + 0);
        float4 g1 = load_coh_x4(gp + scu + 1);
        float4 g2 = load_coh_x4(gp + scu + 2);
        float4 g3 = load_coh_x4(gp + scu + 3);
        wait_vm0();
        {
            float* wrow = hs + sb * EE;
            *(float4*)(wrow + (((scu + 0) ^ sxr) << 2)) = g0;
            *(float4*)(wrow + (((scu + 1) ^ sxr) << 2)) = g1;
            *(float4*)(wrow + (((scu + 2) ^ sxr) << 2)) = g2;
            *(float4*)(wrow + (((scu + 3) ^ sxr) << 2)) = g3;
        }
        __syncthreads();

        // ---- dot products: acc[c][bi] = sum_k w[c][k] * h[bi][kc*32+k] ----
        float acc[3][BATG];
#pragma unroll
        for (int c = 0; c < 3; ++c)
#pragma unroll
            for (int bi = 0; bi < BATG; ++bi) acc[c][bi] = 0.f;

#pragma unroll
        for (int bi = 0; bi < BATG; ++bi) {
            const float* hrow = hs + bi * EE;
#pragma unroll
            for (int q = 0; q < 8; ++q) {
                const int u = kc * 8 + q;
                const float4 hv = *(const float4*)(hrow + ((u ^ (kc & 7)) << 2));
#pragma unroll
                for (int c = 0; c < 3; ++c) {
                    acc[c][bi] += w[c][q*4+0]*hv.x + w[c][q*4+1]*hv.y
                                + w[c][q*4+2]*hv.z + w[c][q*4+3]*hv.w;
                }
            }
        }
        __syncthreads();   // hs reuse next step

        // ---- k-reduction over the 16 kc lanes (lane bits 0..3) ----
#pragma unroll
        for (int m = 1; m < 16; m <<= 1) {
#pragma unroll
            for (int c = 0; c < 3; ++c)
#pragma unroll
                for (int bi = 0; bi < BATG; ++bi)
                    acc[c][bi] += __shfl_xor(acc[c][bi], m, 64);
        }

        // ---- gates + stores (kc==0 lanes; one e per lane) ----
        if (kc == 0) {
#pragma unroll
            for (int bi = 0; bi < BATG; ++bi) {
                const int b = b0 + bi;
                const bool msk = (t < mylen[bi]);
                const float hr = acc[0][bi] + bh[0];
                const float hz = acc[1][bi] + bh[1];
                const float hv_ = acc[2][bi] + bh[2];
                const float rg = 1.f / (1.f + __expf(-(xv[bi][0] + hr)));
                const float zg = 1.f / (1.f + __expf(-(xv[bi][1] + hz)));
                const float ng = tanhf(xv[bi][2] + rg * hv_);
                const float hold = hreg[bi];
                const float hnew = (1.f - zg) * ng + zg * hold;
                const float hout = msk ? hnew : hold;
                hreg[bi] = hout;
                store_coh(hn + (size_t)bi * EE + e, hout);
                y[((size_t)t * BB + b) * EE + e] = msk ? hout : 0.f;
                if (t == TT - 1) finals[(size_t)b * EE + e] = hout;
            }
        }

        // ---- group barrier: drain stores, then 32-wide monotonic epoch ----
        wait_vm0();
        __syncthreads();
        if (tid == 0) {
            const unsigned tgt = (unsigned)BPG * (ebase + (unsigned)t + 1u);
            __hip_atomic_fetch_add(gc, 1u, __ATOMIC_RELAXED,
                                   __HIP_MEMORY_SCOPE_AGENT);
            while (__hip_atomic_load(gc, __ATOMIC_RELAXED,
                                     __HIP_MEMORY_SCOPE_AGENT) < tgt)
                __builtin_amdgcn_s_sleep(1);
        }
        __syncthreads();
    }
}

// ---------------------------------------------------------------------------
extern "C" void kernel_launch(void* const* d_in, const int* in_sizes, int n_in,
                              void* d_out, int out_size, void* d_ws, size_t ws_size,
                              hipStream_t stream) {
    const int* input_batch  = (const int*)d_in[0];
    const int* lens         = (const int*)d_in[1];
    const float* emb        = (const float*)d_in[2];
    const float* W_ih       = (const float*)d_in[3];
    const float* W_hh       = (const float*)d_in[4];
    const float* b_ih       = (const float*)d_in[5];
    const float* b_hh       = (const float*)d_in[6];
    float* out = (float*)d_out;
    float* ws  = (float*)d_ws;

    // workspace layout (float offsets)
    const size_t XPROJ = 0;                          // [T][B][3E]
    const size_t XBUF  = (size_t)TT * BB * N3;       // x_emb, then ys0
    const size_t HBUF  = XBUF + (size_t)TT * BB * EE;
    const size_t CTRL  = HBUF + (size_t)GRP * 2 * BATG * EE;   // 65536 floats
    if (ws_size < (CTRL + 1024) * sizeof(float)) return;

    float* xproj = ws + XPROJ;
    float* xbuf  = ws + XBUF;
    float* hbuf  = ws + HBUF;
    unsigned* ctrl = (unsigned*)(ws + CTRL);

    const size_t OUT_YS = 0;                              // [T][B][E]
    const size_t OUT_FIN = (size_t)TT * BB * EE;          // [L][B][E]

    // zero h ping-pong buffers + barrier counters (ws is poisoned 0xAA)
    (void)hipMemsetAsync(hbuf, 0,
                   ((size_t)GRP * 2 * BATG * EE + 1024) * sizeof(float), stream);

    // x = emb[input_batch]
    embed_k<<<dim3(TT * BB), dim3(128), 0, stream>>>(input_batch, emb, xbuf);

    // ---- layer 0 ----
    gemm_xp<<<dim3(N3 / 128, (TT * BB) / 128), dim3(256), 0, stream>>>(
        xbuf, W_ih, b_ih, xproj);
    gru_scan<<<dim3(256), dim3(256), 0, stream>>>(
        xproj, W_hh, b_hh, lens,
        xbuf /* ys0 (x_emb is dead now) */, hbuf,
        out + OUT_FIN /* finals layer 0 */, ctrl, 0u);

    // ---- layer 1 ----
    gemm_xp<<<dim3(N3 / 128, (TT * BB) / 128), dim3(256), 0, stream>>>(
        xbuf, W_ih + (size_t)N3 * EE, b_ih + N3, xproj);
    (void)hipMemsetAsync(hbuf, 0, (size_t)GRP * 2 * BATG * EE * sizeof(float), stream);
    gru_scan<<<dim3(256), dim3(256), 0, stream>>>(
        xproj, W_hh + (size_t)N3 * EE, b_hh + N3, lens,
        out + OUT_YS /* ys1 = output x */, hbuf,
        out + OUT_FIN + (size_t)BB * EE /* finals layer 1 */, ctrl, 512u);
}

// Round 5
// 11003.329 us; speedup vs baseline: 3.2126x; 1.1052x over previous
//
#include <hip/hip_runtime.h>
#include <cstddef>

// Problem constants
#define TT 512
#define BB 64
#define EE 512
#define N3 1536   // 3*EE

// GRU scan decomposition: 8 batch-groups x 8 batches; 32 blocks/group,
// each block owns 16 e-columns. 256 blocks total, 1 per CU, 512 thr/block.
#define GRP 8
#define BPG 32
#define BATG 8
#define EPB 16

// ---------------------------------------------------------------------------
// Coherent (cross-XCD, IC-level) access helpers: sc0 sc1 = bypass L1+L2.
// ---------------------------------------------------------------------------
__device__ __forceinline__ float4 load_coh_x4(const float4* p) {
    float4 r;
    asm volatile("global_load_dwordx4 %0, %1, off sc0 sc1" : "=v"(r) : "v"(p));
    return r;
}
__device__ __forceinline__ void store_coh(float* p, float v) {
    asm volatile("global_store_dword %0, %1, off sc0 sc1" :: "v"(p), "v"(v) : "memory");
}
__device__ __forceinline__ void wait_vm0() {
    asm volatile("s_waitcnt vmcnt(0)" ::: "memory");
}

// LDS swizzle (16B units): conflict-free for both the 2-unit/thread write
// pattern and the 4-unit/thread (U=4kc+q) read pattern, per-phase verified.
__device__ __forceinline__ int swz(int u) { return u ^ ((u >> 3) & 3); }

// ---------------------------------------------------------------------------
// Embedding gather: xout[i][:] = emb[idx[i]][:], i = t*B+b
// ---------------------------------------------------------------------------
__global__ void embed_k(const int* __restrict__ idx, const float* __restrict__ emb,
                        float* __restrict__ xout) {
    const int i = blockIdx.x;                 // 0..T*B-1
    const int row = idx[i];
    const float4* s = (const float4*)(emb + (size_t)row * EE);
    float4* d = (float4*)(xout + (size_t)i * EE);
    d[threadIdx.x] = s[threadIdx.x];          // 128 threads * float4 = 512 floats
}

// ---------------------------------------------------------------------------
// x_proj GEMM: C[M][N] = A[M][K] * W[N][K]^T + bias[N]
// M=32768, N=1536, K=512. 128x128 tile, 8x8 per thread, fp32.
// ---------------------------------------------------------------------------
__global__ __launch_bounds__(256)
void gemm_xp(const float* __restrict__ A, const float* __restrict__ W,
             const float* __restrict__ bias, float* __restrict__ C) {
    constexpr int K = EE, N = N3;
    __shared__ float As[16][132];
    __shared__ float Bs[16][132];
    const int tid = threadIdx.x;
    const int tx = tid & 15, ty = tid >> 4;
    const int m0 = blockIdx.y * 128, n0 = blockIdx.x * 128;
    const int r = tid >> 1;            // 0..127
    const int kq = (tid & 1) * 8;      // 0 or 8
    const float* Ap = A + (size_t)(m0 + r) * K + kq;
    const float* Wp = W + (size_t)(n0 + r) * K + kq;

    float acc[8][8];
#pragma unroll
    for (int i = 0; i < 8; ++i)
#pragma unroll
        for (int j = 0; j < 8; ++j) acc[i][j] = 0.f;

    for (int k0 = 0; k0 < K; k0 += 16) {
        float4 a0 = *(const float4*)(Ap + k0);
        float4 a1 = *(const float4*)(Ap + k0 + 4);
        float4 b0 = *(const float4*)(Wp + k0);
        float4 b1 = *(const float4*)(Wp + k0 + 4);
        __syncthreads();
        As[kq+0][r] = a0.x; As[kq+1][r] = a0.y; As[kq+2][r] = a0.z; As[kq+3][r] = a0.w;
        As[kq+4][r] = a1.x; As[kq+5][r] = a1.y; As[kq+6][r] = a1.z; As[kq+7][r] = a1.w;
        Bs[kq+0][r] = b0.x; Bs[kq+1][r] = b0.y; Bs[kq+2][r] = b0.z; Bs[kq+3][r] = b0.w;
        Bs[kq+4][r] = b1.x; Bs[kq+5][r] = b1.y; Bs[kq+6][r] = b1.z; Bs[kq+7][r] = b1.w;
        __syncthreads();
#pragma unroll
        for (int kk = 0; kk < 16; ++kk) {
            float av[8], bv[8];
            *(float4*)&av[0] = *(const float4*)&As[kk][ty*8];
            *(float4*)&av[4] = *(const float4*)&As[kk][ty*8+4];
            *(float4*)&bv[0] = *(const float4*)&Bs[kk][tx*8];
            *(float4*)&bv[4] = *(const float4*)&Bs[kk][tx*8+4];
#pragma unroll
            for (int i = 0; i < 8; ++i)
#pragma unroll
                for (int j = 0; j < 8; ++j)
                    acc[i][j] += av[i] * bv[j];
        }
    }
#pragma unroll
    for (int i = 0; i < 8; ++i) {
        float* Crow = C + (size_t)(m0 + ty*8 + i) * N + n0 + tx*8;
#pragma unroll
        for (int j = 0; j < 8; ++j)
            Crow[j] = acc[i][j] + bias[n0 + tx*8 + j];
    }
}

// ---------------------------------------------------------------------------
// GRU recurrence, batch-grouped, 512 threads (8 waves = 2/SIMD for TLP).
// Block = (group g = blockIdx&7, slice sl). Group g owns batches [8g,8g+8);
// block owns e in [16*sl, 16*sl+16).
// Thread (kc = tid&31 -> 16-float k-chunk, et = tid>>5 -> e = e0+et) holds
// Whh rows (r,z,n at its e) x 16 k = 48 weight floats in VGPRs.
// ---------------------------------------------------------------------------
__global__ __launch_bounds__(512, 2)
void gru_scan(const float* __restrict__ xp,   // [T][B][3E] (includes b_ih)
              const float* __restrict__ Whh,  // [3E][E] this layer
              const float* __restrict__ bhh,  // [3E]   this layer
              const int* __restrict__ lens,   // [B]
              float* __restrict__ y,          // [T][B][E]
              float* __restrict__ hbuf,       // [GRP][2][BATG][EE]
              float* __restrict__ finals,     // [B][E]
              unsigned* __restrict__ ctrl, unsigned ebase)
{
    const int g  = blockIdx.x & 7;         // batch group
    const int sl = blockIdx.x >> 3;        // e-slice 0..31
    const int e0 = sl * EPB;
    const int tid = threadIdx.x;
    const int kc = tid & 31;               // k-chunk (16 floats)
    const int et = tid >> 5;               // e within block (0..15)
    const int e  = e0 + et;
    const int b0 = g * BATG;

    // ---- weights: rows (r,z,n at e), k-chunk kc*16..+15 ----
    float w[3][16];
#pragma unroll
    for (int c = 0; c < 3; ++c) {
        const float* wr = Whh + (size_t)(c * EE + e) * EE + kc * 16;
#pragma unroll
        for (int q = 0; q < 4; ++q) {
            float4 v = ((const float4*)wr)[q];
            w[c][q*4+0] = v.x; w[c][q*4+1] = v.y;
            w[c][q*4+2] = v.z; w[c][q*4+3] = v.w;
        }
    }
    float bh[3];
#pragma unroll
    for (int c = 0; c < 3; ++c) bh[c] = bhh[c * EE + e];
    int mylen[BATG];
#pragma unroll
    for (int bi = 0; bi < BATG; ++bi) mylen[bi] = lens[b0 + bi];
    float hreg[BATG];
#pragma unroll
    for (int bi = 0; bi < BATG; ++bi) hreg[bi] = 0.f;

    float* hA = hbuf + (size_t)g * 2 * BATG * EE;
    float* hB = hA + BATG * EE;
    unsigned* gc = ctrl + g * 32;          // per-group counter, 128B apart

    // stager identity: thread stages 32B (2 units of 16B) of the 16KB slice
    const int sb = tid >> 6;               // batch row 0..7
    const int su = (tid & 63) * 2;         // logical 16B-unit base

    __shared__ float hs[BATG * EE];        // 16KB, unit-swizzled per row

    for (int t = 0; t < TT; ++t) {
        const float* hc = (t & 1) ? hB : hA;
        float* hn = (t & 1) ? hA : hB;

        // ---- stage h slice to LDS: 2 coherent dwordx4 loads, pipelined ----
        const float4* gp = (const float4*)(hc + (size_t)sb * EE);
        float4 g0 = load_coh_x4(gp + su);
        float4 g1 = load_coh_x4(gp + su + 1);
        wait_vm0();
        {
            float* wrow = hs + sb * EE;
            *(float4*)(wrow + 4 * swz(su))     = g0;
            *(float4*)(wrow + 4 * swz(su + 1)) = g1;
        }

        // ---- xp loads for this step (issued after the stage-wait so they
        //      are NOT drained by it; compiler waits at gate use) ----
        float xv[BATG][3];
        if (kc == 0) {
            const float* xpt = xp + (size_t)t * BB * N3;
#pragma unroll
            for (int bi = 0; bi < BATG; ++bi) {
                const float* xpb = xpt + (size_t)(b0 + bi) * N3;
#pragma unroll
                for (int c = 0; c < 3; ++c) xv[bi][c] = xpb[c * EE + e];
            }
        }
        __syncthreads();

        // ---- dot products: acc[c][bi] = sum_k w[c][k] * h[bi][kc*16+k] ----
        float acc[3][BATG];
#pragma unroll
        for (int c = 0; c < 3; ++c)
#pragma unroll
            for (int bi = 0; bi < BATG; ++bi) acc[c][bi] = 0.f;

#pragma unroll
        for (int bi = 0; bi < BATG; ++bi) {
            const float* hrow = hs + bi * EE;
#pragma unroll
            for (int q = 0; q < 4; ++q) {
                const int P = (kc * 4 + q) ^ ((kc >> 1) & 3);  // = swz(4kc+q)
                const float4 hv = *(const float4*)(hrow + 4 * P);
#pragma unroll
                for (int c = 0; c < 3; ++c) {
                    acc[c][bi] += w[c][q*4+0]*hv.x + w[c][q*4+1]*hv.y
                                + w[c][q*4+2]*hv.z + w[c][q*4+3]*hv.w;
                }
            }
        }
        __syncthreads();   // hs reuse next step

        // ---- k-reduction over the 32 kc lanes (lane bits 0..4) ----
#pragma unroll
        for (int m = 1; m < 32; m <<= 1) {
#pragma unroll
            for (int c = 0; c < 3; ++c)
#pragma unroll
                for (int bi = 0; bi < BATG; ++bi)
                    acc[c][bi] += __shfl_xor(acc[c][bi], m, 64);
        }

        // ---- gates + stores (kc==0 lanes; one e per lane) ----
        if (kc == 0) {
#pragma unroll
            for (int bi = 0; bi < BATG; ++bi) {
                const int b = b0 + bi;
                const bool msk = (t < mylen[bi]);
                const float hr = acc[0][bi] + bh[0];
                const float hz = acc[1][bi] + bh[1];
                const float hv_ = acc[2][bi] + bh[2];
                const float rg = 1.f / (1.f + __expf(-(xv[bi][0] + hr)));
                const float zg = 1.f / (1.f + __expf(-(xv[bi][1] + hz)));
                const float ng = tanhf(xv[bi][2] + rg * hv_);
                const float hold = hreg[bi];
                const float hnew = (1.f - zg) * ng + zg * hold;
                const float hout = msk ? hnew : hold;
                hreg[bi] = hout;
                store_coh(hn + (size_t)bi * EE + e, hout);
                y[((size_t)t * BB + b) * EE + e] = msk ? hout : 0.f;
                if (t == TT - 1) finals[(size_t)b * EE + e] = hout;
            }
        }

        // ---- group barrier: drain stores, then 32-wide monotonic epoch ----
        wait_vm0();
        __syncthreads();
        if (tid == 0) {
            const unsigned tgt = (unsigned)BPG * (ebase + (unsigned)t + 1u);
            __hip_atomic_fetch_add(gc, 1u, __ATOMIC_RELAXED,
                                   __HIP_MEMORY_SCOPE_AGENT);
            while (__hip_atomic_load(gc, __ATOMIC_RELAXED,
                                     __HIP_MEMORY_SCOPE_AGENT) < tgt)
                __builtin_amdgcn_s_sleep(1);
        }
        __syncthreads();
    }
}

// ---------------------------------------------------------------------------
extern "C" void kernel_launch(void* const* d_in, const int* in_sizes, int n_in,
                              void* d_out, int out_size, void* d_ws, size_t ws_size,
                              hipStream_t stream) {
    const int* input_batch  = (const int*)d_in[0];
    const int* lens         = (const int*)d_in[1];
    const float* emb        = (const float*)d_in[2];
    const float* W_ih       = (const float*)d_in[3];
    const float* W_hh       = (const float*)d_in[4];
    const float* b_ih       = (const float*)d_in[5];
    const float* b_hh       = (const float*)d_in[6];
    float* out = (float*)d_out;
    float* ws  = (float*)d_ws;

    // workspace layout (float offsets)
    const size_t XPROJ = 0;                          // [T][B][3E]
    const size_t XBUF  = (size_t)TT * BB * N3;       // x_emb, then ys0
    const size_t HBUF  = XBUF + (size_t)TT * BB * EE;
    const size_t CTRL  = HBUF + (size_t)GRP * 2 * BATG * EE;
    if (ws_size < (CTRL + 1024) * sizeof(float)) return;

    float* xproj = ws + XPROJ;
    float* xbuf  = ws + XBUF;
    float* hbuf  = ws + HBUF;
    unsigned* ctrl = (unsigned*)(ws + CTRL);

    const size_t OUT_YS = 0;                              // [T][B][E]
    const size_t OUT_FIN = (size_t)TT * BB * EE;          // [L][B][E]

    // zero h ping-pong buffers + barrier counters (ws is poisoned 0xAA)
    (void)hipMemsetAsync(hbuf, 0,
                   ((size_t)GRP * 2 * BATG * EE + 1024) * sizeof(float), stream);

    // x = emb[input_batch]
    embed_k<<<dim3(TT * BB), dim3(128), 0, stream>>>(input_batch, emb, xbuf);

    // ---- layer 0 ----
    gemm_xp<<<dim3(N3 / 128, (TT * BB) / 128), dim3(256), 0, stream>>>(
        xbuf, W_ih, b_ih, xproj);
    gru_scan<<<dim3(256), dim3(512), 0, stream>>>(
        xproj, W_hh, b_hh, lens,
        xbuf /* ys0 (x_emb is dead now) */, hbuf,
        out + OUT_FIN /* finals layer 0 */, ctrl, 0u);

    // ---- layer 1 ----
    gemm_xp<<<dim3(N3 / 128, (TT * BB) / 128), dim3(256), 0, stream>>>(
        xbuf, W_ih + (size_t)N3 * EE, b_ih + N3, xproj);
    (void)hipMemsetAsync(hbuf, 0, (size_t)GRP * 2 * BATG * EE * sizeof(float), stream);
    gru_scan<<<dim3(256), dim3(512), 0, stream>>>(
        xproj, W_hh + (size_t)N3 * EE, b_hh + N3, lens,
        out + OUT_YS /* ys1 = output x */, hbuf,
        out + OUT_FIN + (size_t)BB * EE /* finals layer 1 */, ctrl, 512u);
}

// Round 6
// 9123.158 us; speedup vs baseline: 3.8747x; 1.2061x over previous
//
#include <hip/hip_runtime.h>
#include <cstddef>

// Problem constants
#define TT 512
#define BB 64
#define EE 512
#define N3 1536   // 3*EE

// GRU scan decomposition: 8 batch-groups x 8 batches; 32 blocks/group,
// each block owns 16 e-columns. 256 blocks total, 1 per CU, 512 thr/block.
// Thread = (kc: 16-float k-chunk, 0..31) x (et2: e-pair 0..7) x (bh: bi-half).
#define GRP 8
#define BPG 32
#define BATG 8
#define EPB 16

typedef float v2f __attribute__((ext_vector_type(2)));

// ---------------------------------------------------------------------------
// Coherent (cross-XCD, IC-level) access helpers: sc0 sc1 = bypass L1+L2.
// ---------------------------------------------------------------------------
__device__ __forceinline__ float4 load_coh_x4(const float4* p) {
    float4 r;
    asm volatile("global_load_dwordx4 %0, %1, off sc0 sc1" : "=v"(r) : "v"(p));
    return r;
}
__device__ __forceinline__ void store_coh(float* p, float v) {
    asm volatile("global_store_dword %0, %1, off sc0 sc1" :: "v"(p), "v"(v) : "memory");
}
__device__ __forceinline__ void wait_vm0() {
    asm volatile("s_waitcnt vmcnt(0)" ::: "memory");
}

// Packed fp32 FMA (VOP3P, gfx90a+): d = a*b + c, 2 lanes per instruction.
__device__ __forceinline__ v2f pk_fma(v2f a, v2f b, v2f c) {
    v2f d;
    asm("v_pk_fma_f32 %0, %1, %2, %3" : "=v"(d) : "v"(a), "v"(b), "v"(c));
    return d;
}

// Butterfly-sum helpers: distances 1,2,4,8 via DPP (VALU-only),
// distance 16 via ds_swizzle. Mirror patterns are xor at aligned-group level.
template <int CTRL>
__device__ __forceinline__ float dpp_add(float x) {
    const int yi = __builtin_amdgcn_update_dpp(
        0, __builtin_bit_cast(int, x), CTRL, 0xF, 0xF, true);
    return x + __builtin_bit_cast(float, yi);
}
__device__ __forceinline__ float swz16_add(float x) {
    const int yi = __builtin_amdgcn_ds_swizzle(__builtin_bit_cast(int, x), 0x401F);
    return x + __builtin_bit_cast(float, yi);
}
__device__ __forceinline__ float bfly_sum32(float x) {
    x = dpp_add<0xB1>(x);    // quad_perm [1,0,3,2]  : xor 1
    x = dpp_add<0x4E>(x);    // quad_perm [2,3,0,1]  : xor 2
    x = dpp_add<0x141>(x);   // row_half_mirror      : xor 4 (group level)
    x = dpp_add<0x140>(x);   // row_mirror           : xor 8 (group level)
    x = swz16_add(x);        // ds_swizzle           : xor 16
    return x;
}

// LDS swizzle (16B units): conflict-free for the 2-unit write and the
// U=4kc+q read pattern (each 16-lane phase covers all 8 bank-quads twice).
__device__ __forceinline__ int swz(int u) { return u ^ ((u >> 3) & 3); }

// ---------------------------------------------------------------------------
// Embedding gather: xout[i][:] = emb[idx[i]][:], i = t*B+b
// ---------------------------------------------------------------------------
__global__ void embed_k(const int* __restrict__ idx, const float* __restrict__ emb,
                        float* __restrict__ xout) {
    const int i = blockIdx.x;                 // 0..T*B-1
    const int row = idx[i];
    const float4* s = (const float4*)(emb + (size_t)row * EE);
    float4* d = (float4*)(xout + (size_t)i * EE);
    d[threadIdx.x] = s[threadIdx.x];          // 128 threads * float4 = 512 floats
}

// ---------------------------------------------------------------------------
// x_proj GEMM: C[M][N] = A[M][K] * W[N][K]^T + bias[N]
// M=32768, N=1536, K=512. 128x128 tile, 8x8 per thread, fp32.
// ---------------------------------------------------------------------------
__global__ __launch_bounds__(256)
void gemm_xp(const float* __restrict__ A, const float* __restrict__ W,
             const float* __restrict__ bias, float* __restrict__ C) {
    constexpr int K = EE, N = N3;
    __shared__ float As[16][132];
    __shared__ float Bs[16][132];
    const int tid = threadIdx.x;
    const int tx = tid & 15, ty = tid >> 4;
    const int m0 = blockIdx.y * 128, n0 = blockIdx.x * 128;
    const int r = tid >> 1;            // 0..127
    const int kq = (tid & 1) * 8;      // 0 or 8
    const float* Ap = A + (size_t)(m0 + r) * K + kq;
    const float* Wp = W + (size_t)(n0 + r) * K + kq;

    float acc[8][8];
#pragma unroll
    for (int i = 0; i < 8; ++i)
#pragma unroll
        for (int j = 0; j < 8; ++j) acc[i][j] = 0.f;

    for (int k0 = 0; k0 < K; k0 += 16) {
        float4 a0 = *(const float4*)(Ap + k0);
        float4 a1 = *(const float4*)(Ap + k0 + 4);
        float4 b0 = *(const float4*)(Wp + k0);
        float4 b1 = *(const float4*)(Wp + k0 + 4);
        __syncthreads();
        As[kq+0][r] = a0.x; As[kq+1][r] = a0.y; As[kq+2][r] = a0.z; As[kq+3][r] = a0.w;
        As[kq+4][r] = a1.x; As[kq+5][r] = a1.y; As[kq+6][r] = a1.z; As[kq+7][r] = a1.w;
        Bs[kq+0][r] = b0.x; Bs[kq+1][r] = b0.y; Bs[kq+2][r] = b0.z; Bs[kq+3][r] = b0.w;
        Bs[kq+4][r] = b1.x; Bs[kq+5][r] = b1.y; Bs[kq+6][r] = b1.z; Bs[kq+7][r] = b1.w;
        __syncthreads();
#pragma unroll
        for (int kk = 0; kk < 16; ++kk) {
            float av[8], bv[8];
            *(float4*)&av[0] = *(const float4*)&As[kk][ty*8];
            *(float4*)&av[4] = *(const float4*)&As[kk][ty*8+4];
            *(float4*)&bv[0] = *(const float4*)&Bs[kk][tx*8];
            *(float4*)&bv[4] = *(const float4*)&Bs[kk][tx*8+4];
#pragma unroll
            for (int i = 0; i < 8; ++i)
#pragma unroll
                for (int j = 0; j < 8; ++j)
                    acc[i][j] += av[i] * bv[j];
        }
    }
#pragma unroll
    for (int i = 0; i < 8; ++i) {
        float* Crow = C + (size_t)(m0 + ty*8 + i) * N + n0 + tx*8;
#pragma unroll
        for (int j = 0; j < 8; ++j)
            Crow[j] = acc[i][j] + bias[n0 + tx*8 + j];
    }
}

// ---------------------------------------------------------------------------
// GRU recurrence, batch-grouped, 512 threads (8 waves = 2/SIMD).
// Block = (group g = blockIdx&7, slice sl). Group g owns batches [8g,8g+8);
// block owns e in [16*sl, 16*sl+16).
// Thread (kc = tid&31, et2 = (tid>>5)&7, bh = tid>>8):
//   k-chunk [16kc,16kc+16), e in {e0+et2, e0+et2+8}, bi in [4bh, 4bh+4).
//   6 Whh rows x 16 k = 96 weight floats in VGPRs; dot via v_pk_fma_f32;
//   k-reduction: 4 DPP rounds + 1 ds_swizzle round (LDS ops 120->24/thread).
// ---------------------------------------------------------------------------
__global__ __launch_bounds__(512, 2)
void gru_scan(const float* __restrict__ xp,   // [T][B][3E] (includes b_ih)
              const float* __restrict__ Whh,  // [3E][E] this layer
              const float* __restrict__ bhh,  // [3E]   this layer
              const int* __restrict__ lens,   // [B]
              float* __restrict__ y,          // [T][B][E]
              float* __restrict__ hbuf,       // [GRP][2][BATG][EE]
              float* __restrict__ finals,     // [B][E]
              unsigned* __restrict__ ctrl, unsigned ebase)
{
    const int g  = blockIdx.x & 7;         // batch group
    const int sl = blockIdx.x >> 3;        // e-slice 0..31
    const int e0 = sl * EPB;
    const int tid = threadIdx.x;
    const int kc  = tid & 31;              // k-chunk (16 floats)
    const int et2 = (tid >> 5) & 7;        // e-pair index
    const int bh  = tid >> 8;              // bi-half (0/1)
    const int bq  = bh * 4;                // first group-local bi of my half
    const int b0  = g * BATG;

    // ---- weights: rows (c, e) for e in {e0+et2, e0+et2+8}, k-chunk kc*16 ----
    v2f w2[3][2][8];
#pragma unroll
    for (int c = 0; c < 3; ++c)
#pragma unroll
        for (int ei = 0; ei < 2; ++ei) {
            const int e = e0 + et2 + ei * 8;
            const float* wr = Whh + (size_t)(c * EE + e) * EE + kc * 16;
#pragma unroll
            for (int q = 0; q < 8; ++q) {
                w2[c][ei][q] = v2f{wr[q*2], wr[q*2+1]};
            }
        }
    float bhv[3][2];
#pragma unroll
    for (int c = 0; c < 3; ++c)
#pragma unroll
        for (int ei = 0; ei < 2; ++ei)
            bhv[c][ei] = bhh[c * EE + e0 + et2 + ei * 8];
    int mylen[4];
#pragma unroll
    for (int j = 0; j < 4; ++j) mylen[j] = lens[b0 + bq + j];
    float hreg[4][2] = {{0.f,0.f},{0.f,0.f},{0.f,0.f},{0.f,0.f}};

    float* hA = hbuf + (size_t)g * 2 * BATG * EE;
    float* hB = hA + BATG * EE;
    unsigned* gc = ctrl + g * 32;          // per-group counter, 128B apart

    // stager identity: thread stages 32B (2 units of 16B) of the 16KB slice
    const int sb = tid >> 6;               // batch row 0..7
    const int su = (tid & 63) * 2;         // logical 16B-unit base

    __shared__ float hs[BATG * EE];        // 16KB, unit-swizzled per row

    for (int t = 0; t < TT; ++t) {
        const float* hc = (t & 1) ? hB : hA;
        float* hn = (t & 1) ? hA : hB;

        // ---- stage h slice to LDS: 2 coherent dwordx4 loads, pipelined ----
        const float4* gp = (const float4*)(hc + (size_t)sb * EE);
        float4 g0 = load_coh_x4(gp + su);
        float4 g1 = load_coh_x4(gp + su + 1);
        wait_vm0();
        {
            float* wrow = hs + sb * EE;
            *(float4*)(wrow + 4 * swz(su))     = g0;
            *(float4*)(wrow + 4 * swz(su + 1)) = g1;
        }

        // ---- xp loads (kc==0 lanes; drain at gate use, not at stage) ----
        float xv[4][2][3];
        if (kc == 0) {
            const float* xpt = xp + (size_t)t * BB * N3;
#pragma unroll
            for (int j = 0; j < 4; ++j) {
                const float* xpb = xpt + (size_t)(b0 + bq + j) * N3;
#pragma unroll
                for (int ei = 0; ei < 2; ++ei)
#pragma unroll
                    for (int c = 0; c < 3; ++c)
                        xv[j][ei][c] = xpb[c * EE + e0 + et2 + ei * 8];
            }
        }
        __syncthreads();

        // ---- dot: acc2[c][ei][j] += w2 * h[bq+j][16kc..16kc+16) ----
        v2f acc2[3][2][4];
#pragma unroll
        for (int c = 0; c < 3; ++c)
#pragma unroll
            for (int ei = 0; ei < 2; ++ei)
#pragma unroll
                for (int j = 0; j < 4; ++j) acc2[c][ei][j] = v2f{0.f, 0.f};

#pragma unroll
        for (int j = 0; j < 4; ++j) {
            const float* hrow = hs + (bq + j) * EE;
#pragma unroll
            for (int q = 0; q < 4; ++q) {
                const float4 hv = *(const float4*)(hrow + 4 * swz(4 * kc + q));
                const v2f h2a = v2f{hv.x, hv.y};
                const v2f h2b = v2f{hv.z, hv.w};
#pragma unroll
                for (int c = 0; c < 3; ++c)
#pragma unroll
                    for (int ei = 0; ei < 2; ++ei) {
                        acc2[c][ei][j] = pk_fma(w2[c][ei][2*q],   h2a, acc2[c][ei][j]);
                        acc2[c][ei][j] = pk_fma(w2[c][ei][2*q+1], h2b, acc2[c][ei][j]);
                    }
            }
        }
        __syncthreads();   // hs reuse next step

        // ---- collapse pairs + k-reduction over 32 kc lanes ----
        float acc[3][2][4];
#pragma unroll
        for (int c = 0; c < 3; ++c)
#pragma unroll
            for (int ei = 0; ei < 2; ++ei)
#pragma unroll
                for (int j = 0; j < 4; ++j)
                    acc[c][ei][j] = bfly_sum32(acc2[c][ei][j].x + acc2[c][ei][j].y);

        // ---- gates + stores (kc==0 lanes; 8 outputs each) ----
        if (kc == 0) {
#pragma unroll
            for (int j = 0; j < 4; ++j) {
                const int bl = bq + j;           // group-local bi
                const int b  = b0 + bl;
                const bool msk = (t < mylen[j]);
#pragma unroll
                for (int ei = 0; ei < 2; ++ei) {
                    const int e = e0 + et2 + ei * 8;
                    const float hr  = acc[0][ei][j] + bhv[0][ei];
                    const float hz  = acc[1][ei][j] + bhv[1][ei];
                    const float hv_ = acc[2][ei][j] + bhv[2][ei];
                    const float rg = 1.f / (1.f + __expf(-(xv[j][ei][0] + hr)));
                    const float zg = 1.f / (1.f + __expf(-(xv[j][ei][1] + hz)));
                    const float ng = tanhf(xv[j][ei][2] + rg * hv_);
                    const float hold = hreg[j][ei];
                    const float hnew = (1.f - zg) * ng + zg * hold;
                    const float hout = msk ? hnew : hold;
                    hreg[j][ei] = hout;
                    store_coh(hn + (size_t)bl * EE + e, hout);
                    y[((size_t)t * BB + b) * EE + e] = msk ? hout : 0.f;
                    if (t == TT - 1) finals[(size_t)b * EE + e] = hout;
                }
            }
        }

        // ---- group barrier: drain stores, then 32-wide monotonic epoch ----
        wait_vm0();
        __syncthreads();
        if (tid == 0) {
            const unsigned tgt = (unsigned)BPG * (ebase + (unsigned)t + 1u);
            __hip_atomic_fetch_add(gc, 1u, __ATOMIC_RELAXED,
                                   __HIP_MEMORY_SCOPE_AGENT);
            while (__hip_atomic_load(gc, __ATOMIC_RELAXED,
                                     __HIP_MEMORY_SCOPE_AGENT) < tgt)
                __builtin_amdgcn_s_sleep(1);
        }
        __syncthreads();
    }
}

// ---------------------------------------------------------------------------
extern "C" void kernel_launch(void* const* d_in, const int* in_sizes, int n_in,
                              void* d_out, int out_size, void* d_ws, size_t ws_size,
                              hipStream_t stream) {
    const int* input_batch  = (const int*)d_in[0];
    const int* lens         = (const int*)d_in[1];
    const float* emb        = (const float*)d_in[2];
    const float* W_ih       = (const float*)d_in[3];
    const float* W_hh       = (const float*)d_in[4];
    const float* b_ih       = (const float*)d_in[5];
    const float* b_hh       = (const float*)d_in[6];
    float* out = (float*)d_out;
    float* ws  = (float*)d_ws;

    // workspace layout (float offsets)
    const size_t XPROJ = 0;                          // [T][B][3E]
    const size_t XBUF  = (size_t)TT * BB * N3;       // x_emb, then ys0
    const size_t HBUF  = XBUF + (size_t)TT * BB * EE;
    const size_t CTRL  = HBUF + (size_t)GRP * 2 * BATG * EE;
    if (ws_size < (CTRL + 1024) * sizeof(float)) return;

    float* xproj = ws + XPROJ;
    float* xbuf  = ws + XBUF;
    float* hbuf  = ws + HBUF;
    unsigned* ctrl = (unsigned*)(ws + CTRL);

    const size_t OUT_YS = 0;                              // [T][B][E]
    const size_t OUT_FIN = (size_t)TT * BB * EE;          // [L][B][E]

    // zero h ping-pong buffers + barrier counters (ws is poisoned 0xAA)
    (void)hipMemsetAsync(hbuf, 0,
                   ((size_t)GRP * 2 * BATG * EE + 1024) * sizeof(float), stream);

    // x = emb[input_batch]
    embed_k<<<dim3(TT * BB), dim3(128), 0, stream>>>(input_batch, emb, xbuf);

    // ---- layer 0 ----
    gemm_xp<<<dim3(N3 / 128, (TT * BB) / 128), dim3(256), 0, stream>>>(
        xbuf, W_ih, b_ih, xproj);
    gru_scan<<<dim3(256), dim3(512), 0, stream>>>(
        xproj, W_hh, b_hh, lens,
        xbuf /* ys0 (x_emb is dead now) */, hbuf,
        out + OUT_FIN /* finals layer 0 */, ctrl, 0u);

    // ---- layer 1 ----
    gemm_xp<<<dim3(N3 / 128, (TT * BB) / 128), dim3(256), 0, stream>>>(
        xbuf, W_ih + (size_t)N3 * EE, b_ih + N3, xproj);
    (void)hipMemsetAsync(hbuf, 0, (size_t)GRP * 2 * BATG * EE * sizeof(float), stream);
    gru_scan<<<dim3(256), dim3(512), 0, stream>>>(
        xproj, W_hh + (size_t)N3 * EE, b_hh + N3, lens,
        out + OUT_YS /* ys1 = output x */, hbuf,
        out + OUT_FIN + (size_t)BB * EE /* finals layer 1 */, ctrl, 512u);
}

// Round 7
// 6964.540 us; speedup vs baseline: 5.0756x; 1.3099x over previous
//
#include <hip/hip_runtime.h>
#include <cstddef>

// Problem constants
#define TT 512
#define BB 64
#define EE 512
#define N3 1536   // 3*EE

// GRU scan decomposition: 8 batch-groups x 8 batches; 32 blocks/group,
// each block owns 16 e-columns. 256 blocks total, 1 per CU, 512 thr/block.
// Thread = (kc: 16-float k-chunk, 0..31) x (et2: e-pair 0..7) x (bh: bi-half).
#define GRP 8
#define BPG 32
#define BATG 8
#define EPB 16

typedef float v2f __attribute__((ext_vector_type(2)));

// ---------------------------------------------------------------------------
// Coherent (cross-XCD, IC-level) access helpers: sc0 sc1 = bypass L1+L2.
// ---------------------------------------------------------------------------
__device__ __forceinline__ float4 load_coh_x4(const float4* p) {
    float4 r;
    asm volatile("global_load_dwordx4 %0, %1, off sc0 sc1" : "=v"(r) : "v"(p));
    return r;
}
__device__ __forceinline__ void store_coh(float* p, float v) {
    asm volatile("global_store_dword %0, %1, off sc0 sc1" :: "v"(p), "v"(v) : "memory");
}
__device__ __forceinline__ void wait_vm0() {
    asm volatile("s_waitcnt vmcnt(0)" ::: "memory");
}

// Packed fp32 FMA (VOP3P, gfx90a+): d = a*b + c, 2 lanes per instruction.
__device__ __forceinline__ v2f pk_fma(v2f a, v2f b, v2f c) {
    v2f d;
    asm("v_pk_fma_f32 %0, %1, %2, %3" : "=v"(d) : "v"(a), "v"(b), "v"(c));
    return d;
}

// Fast transcendentals: hw-approx rcp/exp; tanh(x) = 1 - 2/(e^2x + 1)
// (correctly saturates to +-1 via exp overflow/underflow).
__device__ __forceinline__ float fast_rcp(float x) {
    return __builtin_amdgcn_rcpf(x);
}
__device__ __forceinline__ float fast_sigmoid(float x) {
    return fast_rcp(1.f + __expf(-x));
}
__device__ __forceinline__ float fast_tanh(float x) {
    return 1.f - 2.f * fast_rcp(1.f + __expf(2.f * x));
}

// Butterfly-sum helpers: distances 1,2,4,8 via DPP (VALU-only),
// distance 16 via ds_swizzle. Mirror patterns are xor at aligned-group level.
template <int CTRL>
__device__ __forceinline__ float dpp_add(float x) {
    const int yi = __builtin_amdgcn_update_dpp(
        0, __builtin_bit_cast(int, x), CTRL, 0xF, 0xF, true);
    return x + __builtin_bit_cast(float, yi);
}
__device__ __forceinline__ float swz16_add(float x) {
    const int yi = __builtin_amdgcn_ds_swizzle(__builtin_bit_cast(int, x), 0x401F);
    return x + __builtin_bit_cast(float, yi);
}
__device__ __forceinline__ float bfly_sum32(float x) {
    x = dpp_add<0xB1>(x);    // quad_perm [1,0,3,2]  : xor 1
    x = dpp_add<0x4E>(x);    // quad_perm [2,3,0,1]  : xor 2
    x = dpp_add<0x141>(x);   // row_half_mirror      : xor 4 (group level)
    x = dpp_add<0x140>(x);   // row_mirror           : xor 8 (group level)
    x = swz16_add(x);        // ds_swizzle           : xor 16
    return x;
}

// LDS swizzle (16B units): conflict-free for the 2-unit write and the
// U=4kc+q read pattern (each 16-lane phase covers all 8 bank-quads twice).
__device__ __forceinline__ int swz(int u) { return u ^ ((u >> 3) & 3); }

// ---------------------------------------------------------------------------
// Embedding gather: xout[i][:] = emb[idx[i]][:], i = t*B+b
// ---------------------------------------------------------------------------
__global__ void embed_k(const int* __restrict__ idx, const float* __restrict__ emb,
                        float* __restrict__ xout) {
    const int i = blockIdx.x;                 // 0..T*B-1
    const int row = idx[i];
    const float4* s = (const float4*)(emb + (size_t)row * EE);
    float4* d = (float4*)(xout + (size_t)i * EE);
    d[threadIdx.x] = s[threadIdx.x];          // 128 threads * float4 = 512 floats
}

// ---------------------------------------------------------------------------
// x_proj GEMM: C[M][N] = A[M][K] * W[N][K]^T + bias[N]
// M=32768, N=1536, K=512. 128x128 tile, 8x8 per thread, fp32.
// ---------------------------------------------------------------------------
__global__ __launch_bounds__(256)
void gemm_xp(const float* __restrict__ A, const float* __restrict__ W,
             const float* __restrict__ bias, float* __restrict__ C) {
    constexpr int K = EE, N = N3;
    __shared__ float As[16][132];
    __shared__ float Bs[16][132];
    const int tid = threadIdx.x;
    const int tx = tid & 15, ty = tid >> 4;
    const int m0 = blockIdx.y * 128, n0 = blockIdx.x * 128;
    const int r = tid >> 1;            // 0..127
    const int kq = (tid & 1) * 8;      // 0 or 8
    const float* Ap = A + (size_t)(m0 + r) * K + kq;
    const float* Wp = W + (size_t)(n0 + r) * K + kq;

    float acc[8][8];
#pragma unroll
    for (int i = 0; i < 8; ++i)
#pragma unroll
        for (int j = 0; j < 8; ++j) acc[i][j] = 0.f;

    for (int k0 = 0; k0 < K; k0 += 16) {
        float4 a0 = *(const float4*)(Ap + k0);
        float4 a1 = *(const float4*)(Ap + k0 + 4);
        float4 b0 = *(const float4*)(Wp + k0);
        float4 b1 = *(const float4*)(Wp + k0 + 4);
        __syncthreads();
        As[kq+0][r] = a0.x; As[kq+1][r] = a0.y; As[kq+2][r] = a0.z; As[kq+3][r] = a0.w;
        As[kq+4][r] = a1.x; As[kq+5][r] = a1.y; As[kq+6][r] = a1.z; As[kq+7][r] = a1.w;
        Bs[kq+0][r] = b0.x; Bs[kq+1][r] = b0.y; Bs[kq+2][r] = b0.z; Bs[kq+3][r] = b0.w;
        Bs[kq+4][r] = b1.x; Bs[kq+5][r] = b1.y; Bs[kq+6][r] = b1.z; Bs[kq+7][r] = b1.w;
        __syncthreads();
#pragma unroll
        for (int kk = 0; kk < 16; ++kk) {
            float av[8], bv[8];
            *(float4*)&av[0] = *(const float4*)&As[kk][ty*8];
            *(float4*)&av[4] = *(const float4*)&As[kk][ty*8+4];
            *(float4*)&bv[0] = *(const float4*)&Bs[kk][tx*8];
            *(float4*)&bv[4] = *(const float4*)&Bs[kk][tx*8+4];
#pragma unroll
            for (int i = 0; i < 8; ++i)
#pragma unroll
                for (int j = 0; j < 8; ++j)
                    acc[i][j] += av[i] * bv[j];
        }
    }
#pragma unroll
    for (int i = 0; i < 8; ++i) {
        float* Crow = C + (size_t)(m0 + ty*8 + i) * N + n0 + tx*8;
#pragma unroll
        for (int j = 0; j < 8; ++j)
            Crow[j] = acc[i][j] + bias[n0 + tx*8 + j];
    }
}

// ---------------------------------------------------------------------------
// GRU recurrence, batch-grouped, 512 threads (8 waves = 2/SIMD).
// Block = (group g = blockIdx&7, slice sl). Group g owns batches [8g,8g+8);
// block owns e in [16*sl, 16*sl+16).
// Thread (kc = tid&31, et2 = (tid>>5)&7, bh = tid>>8):
//   k-chunk [16kc,16kc+16), e in {e0+et2, e0+et2+8}, bi in [4bh, 4bh+4).
// Epilogue is DISTRIBUTED: butterfly broadcasts all 24 sums to every kc
// lane; lane kc<8 computes the single gate (j=kc>>1, ei=kc&1) via constant-
// index cndmask selects -> gate issue cost ~1/8 of the lane-0-serial form.
// ---------------------------------------------------------------------------
__global__ __launch_bounds__(512, 2)
void gru_scan(const float* __restrict__ xp,   // [T][B][3E] (includes b_ih)
              const float* __restrict__ Whh,  // [3E][E] this layer
              const float* __restrict__ bhh,  // [3E]   this layer
              const int* __restrict__ lens,   // [B]
              float* __restrict__ y,          // [T][B][E]
              float* __restrict__ hbuf,       // [GRP][2][BATG][EE]
              float* __restrict__ finals,     // [B][E]
              unsigned* __restrict__ ctrl, unsigned ebase)
{
    const int g  = blockIdx.x & 7;         // batch group
    const int sl = blockIdx.x >> 3;        // e-slice 0..31
    const int e0 = sl * EPB;
    const int tid = threadIdx.x;
    const int kc  = tid & 31;              // k-chunk (16 floats)
    const int et2 = (tid >> 5) & 7;        // e-pair index
    const int bh  = tid >> 8;              // bi-half (0/1)
    const int bq  = bh * 4;                // first group-local bi of my half
    const int b0  = g * BATG;

    // ---- weights: rows (c, e) for e in {e0+et2, e0+et2+8}, k-chunk kc*16 ----
    v2f w2[3][2][8];
#pragma unroll
    for (int c = 0; c < 3; ++c)
#pragma unroll
        for (int ei = 0; ei < 2; ++ei) {
            const int e = e0 + et2 + ei * 8;
            const float* wr = Whh + (size_t)(c * EE + e) * EE + kc * 16;
#pragma unroll
            for (int q = 0; q < 8; ++q) {
                w2[c][ei][q] = v2f{wr[q*2], wr[q*2+1]};
            }
        }
    float bhv[3][2];
#pragma unroll
    for (int c = 0; c < 3; ++c)
#pragma unroll
        for (int ei = 0; ei < 2; ++ei)
            bhv[c][ei] = bhh[c * EE + e0 + et2 + ei * 8];

    // ---- this lane's epilogue assignment (kc<8 lanes are active) ----
    const int oj  = (kc >> 1) & 3;         // group-local batch sub-index
    const int oei = kc & 1;                // e half
    const int oe  = e0 + et2 + oei * 8;    // output e column
    const int obl = bq + oj;               // group-local batch
    const int ob  = b0 + obl;              // global batch
    const int olen = lens[ob];
    const float obh0 = oei ? bhv[0][1] : bhv[0][0];
    const float obh1 = oei ? bhv[1][1] : bhv[1][0];
    const float obh2 = oei ? bhv[2][1] : bhv[2][0];
    float oh = 0.f;                        // running hidden for my (ob, oe)

    float* hA = hbuf + (size_t)g * 2 * BATG * EE;
    float* hB = hA + BATG * EE;
    unsigned* gc = ctrl + g * 32;          // per-group counter, 128B apart

    // stager identity: thread stages 32B (2 units of 16B) of the 16KB slice
    const int sb = tid >> 6;               // batch row 0..7
    const int su = (tid & 63) * 2;         // logical 16B-unit base

    __shared__ float hs[BATG * EE];        // 16KB, unit-swizzled per row

    for (int t = 0; t < TT; ++t) {
        const float* hc = (t & 1) ? hB : hA;
        float* hn = (t & 1) ? hA : hB;

        // ---- stage h slice to LDS: 2 coherent dwordx4 loads, pipelined ----
        const float4* gp = (const float4*)(hc + (size_t)sb * EE);
        float4 g0 = load_coh_x4(gp + su);
        float4 g1 = load_coh_x4(gp + su + 1);
        wait_vm0();
        {
            float* wrow = hs + sb * EE;
            *(float4*)(wrow + 4 * swz(su))     = g0;
            *(float4*)(wrow + 4 * swz(su + 1)) = g1;
        }

        // ---- xp loads for my output (kc<8 lanes; 3 scalars) ----
        float oxv0, oxv1, oxv2;
        if (kc < 8) {
            const float* xpb = xp + ((size_t)t * BB + ob) * N3;
            oxv0 = xpb[0 * EE + oe];
            oxv1 = xpb[1 * EE + oe];
            oxv2 = xpb[2 * EE + oe];
        }
        __syncthreads();

        // ---- dot: acc2[c][ei][j] += w2 * h[bq+j][16kc..16kc+16) ----
        v2f acc2[3][2][4];
#pragma unroll
        for (int c = 0; c < 3; ++c)
#pragma unroll
            for (int ei = 0; ei < 2; ++ei)
#pragma unroll
                for (int j = 0; j < 4; ++j) acc2[c][ei][j] = v2f{0.f, 0.f};

#pragma unroll
        for (int j = 0; j < 4; ++j) {
            const float* hrow = hs + (bq + j) * EE;
#pragma unroll
            for (int q = 0; q < 4; ++q) {
                const float4 hv = *(const float4*)(hrow + 4 * swz(4 * kc + q));
                const v2f h2a = v2f{hv.x, hv.y};
                const v2f h2b = v2f{hv.z, hv.w};
#pragma unroll
                for (int c = 0; c < 3; ++c)
#pragma unroll
                    for (int ei = 0; ei < 2; ++ei) {
                        acc2[c][ei][j] = pk_fma(w2[c][ei][2*q],   h2a, acc2[c][ei][j]);
                        acc2[c][ei][j] = pk_fma(w2[c][ei][2*q+1], h2b, acc2[c][ei][j]);
                    }
            }
        }
        __syncthreads();   // hs reuse next step

        // ---- collapse pairs + k-reduction (broadcasts to all kc lanes) ----
        float acc[3][2][4];
#pragma unroll
        for (int c = 0; c < 3; ++c)
#pragma unroll
            for (int ei = 0; ei < 2; ++ei)
#pragma unroll
                for (int j = 0; j < 4; ++j)
                    acc[c][ei][j] = bfly_sum32(acc2[c][ei][j].x + acc2[c][ei][j].y);

        // ---- distributed gate: lane kc<8 computes output (oj, oei) ----
        if (kc < 8) {
            float oa[3];
#pragma unroll
            for (int c = 0; c < 3; ++c) {
                const float x0 = oei ? acc[c][1][0] : acc[c][0][0];
                const float x1 = oei ? acc[c][1][1] : acc[c][0][1];
                const float x2 = oei ? acc[c][1][2] : acc[c][0][2];
                const float x3 = oei ? acc[c][1][3] : acc[c][0][3];
                const float y01 = (oj & 1) ? x1 : x0;
                const float y23 = (oj & 1) ? x3 : x2;
                oa[c] = (oj & 2) ? y23 : y01;
            }
            const bool msk = (t < olen);
            const float rg = fast_sigmoid(oxv0 + oa[0] + obh0);
            const float zg = fast_sigmoid(oxv1 + oa[1] + obh1);
            const float ng = fast_tanh(oxv2 + rg * (oa[2] + obh2));
            const float hnew = (1.f - zg) * ng + zg * oh;
            const float hout = msk ? hnew : oh;
            oh = hout;
            store_coh(hn + (size_t)obl * EE + oe, hout);
            y[((size_t)t * BB + ob) * EE + oe] = msk ? hout : 0.f;
            if (t == TT - 1) finals[(size_t)ob * EE + oe] = hout;
        }

        // ---- group barrier: drain stores, then 32-wide monotonic epoch ----
        wait_vm0();
        __syncthreads();
        if (tid == 0) {
            const unsigned tgt = (unsigned)BPG * (ebase + (unsigned)t + 1u);
            __hip_atomic_fetch_add(gc, 1u, __ATOMIC_RELAXED,
                                   __HIP_MEMORY_SCOPE_AGENT);
            while (__hip_atomic_load(gc, __ATOMIC_RELAXED,
                                     __HIP_MEMORY_SCOPE_AGENT) < tgt)
                __builtin_amdgcn_s_sleep(1);
        }
        __syncthreads();
    }
}

// ---------------------------------------------------------------------------
extern "C" void kernel_launch(void* const* d_in, const int* in_sizes, int n_in,
                              void* d_out, int out_size, void* d_ws, size_t ws_size,
                              hipStream_t stream) {
    const int* input_batch  = (const int*)d_in[0];
    const int* lens         = (const int*)d_in[1];
    const float* emb        = (const float*)d_in[2];
    const float* W_ih       = (const float*)d_in[3];
    const float* W_hh       = (const float*)d_in[4];
    const float* b_ih       = (const float*)d_in[5];
    const float* b_hh       = (const float*)d_in[6];
    float* out = (float*)d_out;
    float* ws  = (float*)d_ws;

    // workspace layout (float offsets)
    const size_t XPROJ = 0;                          // [T][B][3E]
    const size_t XBUF  = (size_t)TT * BB * N3;       // x_emb, then ys0
    const size_t HBUF  = XBUF + (size_t)TT * BB * EE;
    const size_t CTRL  = HBUF + (size_t)GRP * 2 * BATG * EE;
    if (ws_size < (CTRL + 1024) * sizeof(float)) return;

    float* xproj = ws + XPROJ;
    float* xbuf  = ws + XBUF;
    float* hbuf  = ws + HBUF;
    unsigned* ctrl = (unsigned*)(ws + CTRL);

    const size_t OUT_YS = 0;                              // [T][B][E]
    const size_t OUT_FIN = (size_t)TT * BB * EE;          // [L][B][E]

    // zero h ping-pong buffers + barrier counters (ws is poisoned 0xAA)
    (void)hipMemsetAsync(hbuf, 0,
                   ((size_t)GRP * 2 * BATG * EE + 1024) * sizeof(float), stream);

    // x = emb[input_batch]
    embed_k<<<dim3(TT * BB), dim3(128), 0, stream>>>(input_batch, emb, xbuf);

    // ---- layer 0 ----
    gemm_xp<<<dim3(N3 / 128, (TT * BB) / 128), dim3(256), 0, stream>>>(
        xbuf, W_ih, b_ih, xproj);
    gru_scan<<<dim3(256), dim3(512), 0, stream>>>(
        xproj, W_hh, b_hh, lens,
        xbuf /* ys0 (x_emb is dead now) */, hbuf,
        out + OUT_FIN /* finals layer 0 */, ctrl, 0u);

    // ---- layer 1 ----
    gemm_xp<<<dim3(N3 / 128, (TT * BB) / 128), dim3(256), 0, stream>>>(
        xbuf, W_ih + (size_t)N3 * EE, b_ih + N3, xproj);
    (void)hipMemsetAsync(hbuf, 0, (size_t)GRP * 2 * BATG * EE * sizeof(float), stream);
    gru_scan<<<dim3(256), dim3(512), 0, stream>>>(
        xproj, W_hh + (size_t)N3 * EE, b_hh + N3, lens,
        out + OUT_YS /* ys1 = output x */, hbuf,
        out + OUT_FIN + (size_t)BB * EE /* finals layer 1 */, ctrl, 512u);
}